// Round 1
// baseline (726.859 us; speedup 1.0000x reference)
//
#include <hip/hip_runtime.h>

namespace {
constexpr int B = 16;
constexpr int N = 900;   // queries (columns)
constexpr int T = 64;    // targets (rows)
constexpr int L = 96;
constexpr int KE = 15;   // columns per lane: 64*15 = 960 >= 900
constexpr float BIGF = 1e9f;
}

// Faithful reproduction of the reference cost, FP-contract off to match numpy
__device__ __forceinline__ float cost_elem(float cx, float cy, float w, float h,
                                           float prob,
                                           float tx0, float ty0, float tx1, float ty1) {
#pragma clang fp contract(off)
  float hw = w * 0.5f, hh = h * 0.5f;          // w/2 exact
  float x0 = cx - hw, y0 = cy - hh;
  float x1 = cx + hw, y1 = cy + hh;
  // L1 between xywh (out) and xyxy (tgt) — faithful to reference
  float cb = fabsf(cx - tx0);
  cb = cb + fabsf(cy - ty0);
  cb = cb + fabsf(w - tx1);
  cb = cb + fabsf(h - ty1);
  float area1 = (x1 - x0) * (y1 - y0);
  float area2 = (tx1 - tx0) * (ty1 - ty0);
  float iw = fmaxf(fminf(x1, tx1) - fmaxf(x0, tx0), 0.0f);
  float ih = fmaxf(fminf(y1, ty1) - fmaxf(y0, ty0), 0.0f);
  float inter = iw * ih;
  float uni = (area1 + area2) - inter;
  float iou = inter / uni;
  float ew = fmaxf(fmaxf(x1, tx1) - fminf(x0, tx0), 0.0f);
  float eh = fmaxf(fmaxf(y1, ty1) - fminf(y0, ty0), 0.0f);
  float ae = ew * eh;
  float giou = iou - (ae - uni) / ae;
  float c = cb * 5.0f;
  c = c + giou * (-2.0f);   // + cost_giou*2, cost_giou = -giou
  c = c - prob;             // + cost_class
  return c;
}

__global__ __launch_bounds__(256) void cost_kernel(const float* __restrict__ outputs,
                                                   const float* __restrict__ targets,
                                                   float* __restrict__ cost) {
  __shared__ float tb[T * 4];
  __shared__ int tc[T];
  int b = blockIdx.y;
  int tid = threadIdx.x;
  if (tid < T) {
    const float* tr = targets + (size_t)(b * T + tid) * 5;
    tb[tid * 4 + 0] = tr[0];
    tb[tid * 4 + 1] = tr[1];
    tb[tid * 4 + 2] = tr[2];
    tb[tid * 4 + 3] = tr[3];
    tc[tid] = (int)tr[4];
  }
  __syncthreads();
  int n = blockIdx.x * 256 + tid;
  if (n >= N) return;
  const float* orow = outputs + (size_t)(b * N + n) * L;
  float4 box = *reinterpret_cast<const float4*>(orow);
  float* cbase = cost + (size_t)b * T * N + n;
  for (int t = 0; t < T; ++t) {
    float pc = orow[5 + tc[t]];
    float c = cost_elem(box.x, box.y, box.z, box.w, pc,
                        tb[t * 4 + 0], tb[t * 4 + 1], tb[t * 4 + 2], tb[t * 4 + 3]);
    cbase[(size_t)t * N] = c;
  }
}

// One wave (64 lanes) per batch. JV shortest-augmenting-path, faithful to reference.
template <bool PRECOMP>
__global__ __launch_bounds__(64) void hungarian_kernel(const float* __restrict__ outputs,
                                                       const float* __restrict__ targets,
                                                       const float* __restrict__ cost,
                                                       int* __restrict__ out) {
  __shared__ float u[T + 1];
  __shared__ float tb[T * 4];
  __shared__ int tc[T];
  __shared__ int p[N + 1];
  __shared__ int way[N + 1];
  __shared__ int qq[T];

  int b = blockIdx.x;
  int lane = threadIdx.x;

  // ---- init ----
  for (int j = lane; j <= N; j += 64) p[j] = 0;
  u[lane] = 0.0f;
  if (lane == 0) u[T] = 0.0f;
  {
    const float* tr = targets + (size_t)(b * T + lane) * 5;
    tb[lane * 4 + 0] = tr[0];
    tb[lane * 4 + 1] = tr[1];
    tb[lane * 4 + 2] = tr[2];
    tb[lane * 4 + 3] = tr[3];
    tc[lane] = (int)tr[4];
  }
  float v[KE], minv[KE];
#pragma unroll
  for (int k = 0; k < KE; ++k) v[k] = 0.0f;

  const float* crow_base = PRECOMP ? (cost + (size_t)b * T * N) : nullptr;
  const float* obase = outputs + (size_t)b * N * L;

  __syncthreads();

  for (int i = 1; i <= T; ++i) {
    if (lane == 0) p[0] = i;
    unsigned usedmask = 0;
#pragma unroll
    for (int k = 0; k < KE; ++k) minv[k] = BIGF;
    int j0 = 0;

    for (int guard = 0; guard < T + 4; ++guard) {
      __syncthreads();  // order u/p/way updates from previous phase (single-wave: cheap)
      if (j0 > 0) {
        int owner = (j0 - 1) & 63;
        if (lane == owner) usedmask |= (1u << ((j0 - 1) >> 6));
      }
      int i0 = p[j0];   // uniform LDS read
      float ui0 = u[i0];
      int trow = i0 - 1;
      float tx0 = tb[trow * 4 + 0], ty0 = tb[trow * 4 + 1];
      float tx1 = tb[trow * 4 + 2], ty1 = tb[trow * 4 + 3];
      int cls = tc[trow];

      float lbest = BIGF;
      int lbj = 0x7fffffff;
#pragma unroll
      for (int k = 0; k < KE; ++k) {
        int j = 1 + lane + (k << 6);
        if (j <= N) {
          float c;
          if (PRECOMP) {
            c = crow_base[(size_t)trow * N + (j - 1)];
          } else {
            const float* orow = obase + (size_t)(j - 1) * L;
            float4 box = *reinterpret_cast<const float4*>(orow);
            float pc = orow[5 + cls];
            c = cost_elem(box.x, box.y, box.z, box.w, pc, tx0, ty0, tx1, ty1);
          }
          float cur = (c - ui0) - v[k];
          if (!((usedmask >> k) & 1u)) {
            if (cur < minv[k]) {
              minv[k] = cur;
              way[j] = j0;
            }
            // tie-break: lowest j (jnp.argmin takes first occurrence)
            if (minv[k] < lbest || (minv[k] == lbest && j < lbj)) {
              lbest = minv[k];
              lbj = j;
            }
          }
        }
      }
      // 64-lane butterfly argmin with index tie-break
#pragma unroll
      for (int off = 32; off >= 1; off >>= 1) {
        float ov = __shfl_xor(lbest, off);
        int oj = __shfl_xor(lbj, off);
        if (ov < lbest || (ov == lbest && oj < lbj)) {
          lbest = ov;
          lbj = oj;
        }
      }
      float delta = lbest;
      int j1 = lbj;

      // updates: used j -> v[j]-=delta, u[p[j]]+=delta; unused -> minv[j]-=delta.
      // j=0 is always used (p[0]=i): lane 0 handles it.
      if (lane == 0) u[i] += delta;
#pragma unroll
      for (int k = 0; k < KE; ++k) {
        int j = 1 + lane + (k << 6);
        if (j <= N) {
          if ((usedmask >> k) & 1u) {
            v[k] -= delta;
            int r = p[j];   // distinct rows across used j: no write conflicts
            u[r] += delta;
          } else {
            minv[k] -= delta;
          }
        }
      }
      j0 = j1;
      if (p[j0] == 0) break;  // uniform
    }

    __syncthreads();
    // augment along way[] chain (uniform LDS reads; lane 0 writes)
    for (int guard = 0; guard < T + 4 && j0 != 0; ++guard) {
      int jn = way[j0];
      int pv = p[jn];
      if (lane == 0) p[j0] = pv;
      j0 = jn;
    }
  }

  __syncthreads();
  // extract q: p[j] = row assigned to column j (1-indexed)
#pragma unroll
  for (int k = 0; k < KE; ++k) {
    int j = 1 + lane + (k << 6);
    if (j <= N) {
      int r = p[j];
      if (r > 0) qq[r - 1] = j - 1;
    }
  }
  __syncthreads();
  // sort pairs by query index: rank of q_t among all q (distinct values)
  int qt = qq[lane];
  int rank = 0;
  for (int s = 0; s < T; ++s) rank += (qq[s] < qt) ? 1 : 0;
  out[b * T + rank] = qt;                 // i_idx (sorted query indices)
  out[B * T + b * T + rank] = lane;       // j_idx (target index per sorted position)
}

extern "C" void kernel_launch(void* const* d_in, const int* in_sizes, int n_in,
                              void* d_out, int out_size, void* d_ws, size_t ws_size,
                              hipStream_t stream) {
  const float* outputs = (const float*)d_in[0];
  const float* targets = (const float*)d_in[1];
  int* out = (int*)d_out;

  size_t cost_bytes = (size_t)B * T * N * sizeof(float);
  if (ws_size >= cost_bytes) {
    float* cost = (float*)d_ws;
    cost_kernel<<<dim3((N + 255) / 256, B), 256, 0, stream>>>(outputs, targets, cost);
    hungarian_kernel<true><<<B, 64, 0, stream>>>(outputs, targets, cost, out);
  } else {
    hungarian_kernel<false><<<B, 64, 0, stream>>>(outputs, targets, nullptr, out);
  }
}

// Round 2
// 373.182 us; speedup vs baseline: 1.9477x; 1.9477x over previous
//
#include <hip/hip_runtime.h>

namespace {
constexpr int B = 16;
constexpr int N = 900;   // queries (columns)
constexpr int T = 64;    // targets (rows)
constexpr int L = 96;
constexpr int KE = 15;   // columns per lane: 64*15 = 960 >= 900
constexpr float BIGF = 1e9f;
}

// Faithful reproduction of the reference cost, FP-contract off to match numpy
__device__ __forceinline__ float cost_elem(float cx, float cy, float w, float h,
                                           float prob,
                                           float tx0, float ty0, float tx1, float ty1) {
#pragma clang fp contract(off)
  float hw = w * 0.5f, hh = h * 0.5f;
  float x0 = cx - hw, y0 = cy - hh;
  float x1 = cx + hw, y1 = cy + hh;
  float cb = fabsf(cx - tx0);
  cb = cb + fabsf(cy - ty0);
  cb = cb + fabsf(w - tx1);
  cb = cb + fabsf(h - ty1);
  float area1 = (x1 - x0) * (y1 - y0);
  float area2 = (tx1 - tx0) * (ty1 - ty0);
  float iw = fmaxf(fminf(x1, tx1) - fmaxf(x0, tx0), 0.0f);
  float ih = fmaxf(fminf(y1, ty1) - fmaxf(y0, ty0), 0.0f);
  float inter = iw * ih;
  float uni = (area1 + area2) - inter;
  float iou = inter / uni;
  float ew = fmaxf(fmaxf(x1, tx1) - fminf(x0, tx0), 0.0f);
  float eh = fmaxf(fmaxf(y1, ty1) - fminf(y0, ty0), 0.0f);
  float ae = ew * eh;
  float giou = iou - (ae - uni) / ae;
  float c = cb * 5.0f;
  c = c + giou * (-2.0f);
  c = c - prob;
  return c;
}

__global__ __launch_bounds__(256) void cost_kernel(const float* __restrict__ outputs,
                                                   const float* __restrict__ targets,
                                                   float* __restrict__ cost) {
  __shared__ float tb[T * 4];
  __shared__ int tc[T];
  int b = blockIdx.y;
  int tid = threadIdx.x;
  if (tid < T) {
    const float* tr = targets + (size_t)(b * T + tid) * 5;
    tb[tid * 4 + 0] = tr[0];
    tb[tid * 4 + 1] = tr[1];
    tb[tid * 4 + 2] = tr[2];
    tb[tid * 4 + 3] = tr[3];
    tc[tid] = (int)tr[4];
  }
  __syncthreads();
  int n = blockIdx.x * 256 + tid;
  if (n >= N) return;
  const float* orow = outputs + (size_t)(b * N + n) * L;
  float4 box = *reinterpret_cast<const float4*>(orow);
  float* cbase = cost + (size_t)b * T * N + n;
  for (int t = 0; t < T; ++t) {
    float pc = orow[5 + tc[t]];
    float c = cost_elem(box.x, box.y, box.z, box.w, pc,
                        tb[t * 4 + 0], tb[t * 4 + 1], tb[t * 4 + 2], tb[t * 4 + 3]);
    cbase[(size_t)t * N] = c;
  }
}

// DPP-based lexicographic (val, j) min reduction step, carrying payload p.
// bound_ctrl=false + old=self => invalid source lanes compare against self (no-op).
template <int CTRL>
__device__ __forceinline__ void dpp_step(float& bv, int& bj, int& bp) {
  int v2i = __builtin_amdgcn_update_dpp(__float_as_int(bv), __float_as_int(bv),
                                        CTRL, 0xf, 0xf, false);
  int j2 = __builtin_amdgcn_update_dpp(bj, bj, CTRL, 0xf, 0xf, false);
  int p2 = __builtin_amdgcn_update_dpp(bp, bp, CTRL, 0xf, 0xf, false);
  float v2 = __int_as_float(v2i);
  bool take = (v2 < bv) || (v2 == bv && j2 < bj);
  bv = take ? v2 : bv;
  bj = take ? j2 : bj;
  bp = take ? p2 : bp;
}

__device__ __forceinline__ void wave_argmin(float& bv, int& bj, int& bp) {
  dpp_step<0x111>(bv, bj, bp);  // row_shr:1
  dpp_step<0x112>(bv, bj, bp);  // row_shr:2
  dpp_step<0x114>(bv, bj, bp);  // row_shr:4
  dpp_step<0x118>(bv, bj, bp);  // row_shr:8 -> lane15/31/47/63 hold row mins
  dpp_step<0x142>(bv, bj, bp);  // row_bcast:15
  dpp_step<0x143>(bv, bj, bp);  // row_bcast:31 -> lane 63 holds full min
}

// One wave (64 lanes) per batch. JV shortest-augmenting-path, bit-faithful to reference.
template <bool PRECOMP>
__global__ __launch_bounds__(64) void hungarian_kernel(const float* __restrict__ outputs,
                                                       const float* __restrict__ targets,
                                                       const float* __restrict__ cost,
                                                       int* __restrict__ out) {
  __shared__ float u_lds[T + 1];
  __shared__ float tb[T * 4];
  __shared__ int tc[T];
  __shared__ int p_lds[N + 1];
  __shared__ int way_lds[N + 1];
  __shared__ int qq[T];

  int b = blockIdx.x;
  int lane = threadIdx.x;

  // ---- init (single wave: LDS ops are in-order, no barriers needed) ----
  for (int j = lane; j <= N; j += 64) p_lds[j] = 0;
  u_lds[lane] = 0.0f;
  if (lane == 0) u_lds[T] = 0.0f;
  if (!PRECOMP) {
    const float* tr = targets + (size_t)(b * T + lane) * 5;
    tb[lane * 4 + 0] = tr[0];
    tb[lane * 4 + 1] = tr[1];
    tb[lane * 4 + 2] = tr[2];
    tb[lane * 4 + 3] = tr[3];
    tc[lane] = (int)tr[4];
  }
  float v[KE], minv[KE];
#pragma unroll
  for (int k = 0; k < KE; ++k) v[k] = 0.0f;

  const float* cost_b = PRECOMP ? (cost + (size_t)b * T * N) : nullptr;
  const float* obase = outputs + (size_t)b * N * L;

  __syncthreads();

  for (int i = 1; i <= T; ++i) {
#pragma unroll
    for (int k = 0; k < KE; ++k) minv[k] = BIGF;
    unsigned usedmask = 0;
    int j0 = 0;   // column being expanded
    int p0 = i;   // p[j0]; p[0] == i conceptually (never stored)

    for (int guard = 0; guard <= T + 2; ++guard) {
      // mark j0 used (owner lane)
      if (j0 > 0) {
        int jj = j0 - 1;
        if (lane == (jj & 63)) usedmask |= (1u << (jj >> 6));
      }
      int trow = p0 - 1;

      // issue cost-row loads ASAP (L2-resident); u read hides under them
      float c[KE];
      if (PRECOMP) {
        const float* crow = cost_b + (size_t)trow * N;
#pragma unroll
        for (int k = 0; k < KE; ++k) {
          int idx = lane + (k << 6);
          c[k] = (idx < N) ? crow[idx] : 0.0f;
        }
      } else {
        float tx0 = tb[trow * 4 + 0], ty0 = tb[trow * 4 + 1];
        float tx1 = tb[trow * 4 + 2], ty1 = tb[trow * 4 + 3];
        int cls = tc[trow];
#pragma unroll
        for (int k = 0; k < KE; ++k) {
          int idx = lane + (k << 6);
          if (idx < N) {
            const float* orow = obase + (size_t)idx * L;
            float4 box = *reinterpret_cast<const float4*>(orow);
            float pc = orow[5 + cls];
            c[k] = cost_elem(box.x, box.y, box.z, box.w, pc, tx0, ty0, tx1, ty1);
          } else {
            c[k] = 0.0f;
          }
        }
      }
      float ui0 = u_lds[p0];

      // per-lane candidate: reference-exact cur/minv/way updates
      float bv = BIGF;
      int bj = N;
#pragma unroll
      for (int k = 0; k < KE; ++k) {
        int j = 1 + lane + (k << 6);
        if (j <= N && !((usedmask >> k) & 1u)) {
          float cur = (c[k] - ui0) - v[k];
          if (cur < minv[k]) {
            minv[k] = cur;
            way_lds[j] = j0;
          }
          if (minv[k] < bv) {  // strict <: first-index tie-break (ascending j per lane)
            bv = minv[k];
            bj = j;
          }
        }
      }

      // prefetch p[candidate] (latency hidden under the DPP reduction)
      int bp = p_lds[bj];
      wave_argmin(bv, bj, bp);
      float delta = __int_as_float(__builtin_amdgcn_readlane(__float_as_int(bv), 63));
      int j1 = __builtin_amdgcn_readlane(bj, 63);
      int p1 = __builtin_amdgcn_readlane(bp, 63);

      // reference-exact potential updates
      if (lane == 0) u_lds[i] += delta;  // j=0 slot: p[0] = i
#pragma unroll
      for (int k = 0; k < KE; ++k) {
        if ((usedmask >> k) & 1u) {
          v[k] -= delta;
          int j = 1 + lane + (k << 6);
          int r = p_lds[j];     // distinct rows across used j
          u_lds[r] += delta;
        }
        minv[k] -= delta;       // used slots: garbage, but masked out above
      }

      j0 = j1;
      p0 = p1;
      if (p0 == 0) break;
    }

    // augment along way[] chain (uniform LDS reads; lane 0 writes)
    int jc = j0;
    for (int guard = 0; guard <= T + 2 && jc != 0; ++guard) {
      int jn = way_lds[jc];
      int pv = (jn == 0) ? i : p_lds[jn];
      if (lane == 0) p_lds[jc] = pv;
      jc = jn;
    }
  }

  __syncthreads();
  // extract q: p[j] = row assigned to column j (1-indexed)
#pragma unroll
  for (int k = 0; k < KE; ++k) {
    int j = 1 + lane + (k << 6);
    if (j <= N) {
      int r = p_lds[j];
      if (r > 0) qq[r - 1] = j - 1;
    }
  }
  __syncthreads();
  // sort pairs by query index: rank of q_t among all q (distinct values)
  int qt = qq[lane];
  int rank = 0;
  for (int s = 0; s < T; ++s) rank += (qq[s] < qt) ? 1 : 0;
  out[b * T + rank] = qt;            // i_idx (sorted query indices)
  out[B * T + b * T + rank] = lane;  // j_idx (target per sorted position)
}

extern "C" void kernel_launch(void* const* d_in, const int* in_sizes, int n_in,
                              void* d_out, int out_size, void* d_ws, size_t ws_size,
                              hipStream_t stream) {
  const float* outputs = (const float*)d_in[0];
  const float* targets = (const float*)d_in[1];
  int* out = (int*)d_out;

  size_t cost_bytes = (size_t)B * T * N * sizeof(float);
  if (ws_size >= cost_bytes) {
    float* cost = (float*)d_ws;
    cost_kernel<<<dim3((N + 255) / 256, B), 256, 0, stream>>>(outputs, targets, cost);
    hungarian_kernel<true><<<B, 64, 0, stream>>>(outputs, targets, cost, out);
  } else {
    hungarian_kernel<false><<<B, 64, 0, stream>>>(outputs, targets, nullptr, out);
  }
}

// Round 3
// 316.202 us; speedup vs baseline: 2.2987x; 1.1802x over previous
//
#include <hip/hip_runtime.h>

namespace {
constexpr int B = 16;
constexpr int N = 900;   // queries (columns)
constexpr int NP = 960;  // padded cost-row stride (floats), 16B-aligned rows
constexpr int T = 64;    // targets (rows)
constexpr int L = 96;
constexpr float BIGF = 1e9f;
}

// Faithful reproduction of the reference cost, FP-contract off to match numpy
__device__ __forceinline__ float cost_elem(float cx, float cy, float w, float h,
                                           float prob,
                                           float tx0, float ty0, float tx1, float ty1) {
#pragma clang fp contract(off)
  float hw = w * 0.5f, hh = h * 0.5f;
  float x0 = cx - hw, y0 = cy - hh;
  float x1 = cx + hw, y1 = cy + hh;
  float cb = fabsf(cx - tx0);
  cb = cb + fabsf(cy - ty0);
  cb = cb + fabsf(w - tx1);
  cb = cb + fabsf(h - ty1);
  float area1 = (x1 - x0) * (y1 - y0);
  float area2 = (tx1 - tx0) * (ty1 - ty0);
  float iw = fmaxf(fminf(x1, tx1) - fmaxf(x0, tx0), 0.0f);
  float ih = fmaxf(fminf(y1, ty1) - fmaxf(y0, ty0), 0.0f);
  float inter = iw * ih;
  float uni = (area1 + area2) - inter;
  float iou = inter / uni;
  float ew = fmaxf(fmaxf(x1, tx1) - fminf(x0, tx0), 0.0f);
  float eh = fmaxf(fmaxf(y1, ty1) - fminf(y0, ty0), 0.0f);
  float ae = ew * eh;
  float giou = iou - (ae - uni) / ae;
  float c = cb * 5.0f;
  c = c + giou * (-2.0f);
  c = c - prob;
  return c;
}

__global__ __launch_bounds__(256) void cost_kernel(const float* __restrict__ outputs,
                                                   const float* __restrict__ targets,
                                                   float* __restrict__ cost) {
  __shared__ float tb[T * 4];
  __shared__ int tc[T];
  int b = blockIdx.y;
  int tid = threadIdx.x;
  if (tid < T) {
    const float* tr = targets + (size_t)(b * T + tid) * 5;
    tb[tid * 4 + 0] = tr[0];
    tb[tid * 4 + 1] = tr[1];
    tb[tid * 4 + 2] = tr[2];
    tb[tid * 4 + 3] = tr[3];
    tc[tid] = (int)tr[4];
  }
  __syncthreads();
  int n = blockIdx.x * 256 + tid;
  if (n >= N) return;
  const float* orow = outputs + (size_t)(b * N + n) * L;
  float4 box = *reinterpret_cast<const float4*>(orow);
  float* cbase = cost + (size_t)b * T * NP + n;
  for (int t = 0; t < T; ++t) {
    float pc = orow[5 + tc[t]];
    float c = cost_elem(box.x, box.y, box.z, box.w, pc,
                        tb[t * 4 + 0], tb[t * 4 + 1], tb[t * 4 + 2], tb[t * 4 + 3]);
    cbase[(size_t)t * NP] = c;
  }
}

// DPP lexicographic (val, j) min step carrying payload p.
template <int CTRL>
__device__ __forceinline__ void dpp_step(float& bv, int& bj, int& bp) {
  int v2i = __builtin_amdgcn_update_dpp(__float_as_int(bv), __float_as_int(bv),
                                        CTRL, 0xf, 0xf, false);
  int j2 = __builtin_amdgcn_update_dpp(bj, bj, CTRL, 0xf, 0xf, false);
  int p2 = __builtin_amdgcn_update_dpp(bp, bp, CTRL, 0xf, 0xf, false);
  float v2 = __int_as_float(v2i);
  bool take = (v2 < bv) || (v2 == bv && j2 < bj);
  bv = take ? v2 : bv;
  bj = take ? j2 : bj;
  bp = take ? p2 : bp;
}

__device__ __forceinline__ void wave_argmin(float& bv, int& bj, int& bp) {
  dpp_step<0x111>(bv, bj, bp);  // row_shr:1
  dpp_step<0x112>(bv, bj, bp);  // row_shr:2
  dpp_step<0x114>(bv, bj, bp);  // row_shr:4
  dpp_step<0x118>(bv, bj, bp);  // row_shr:8
  dpp_step<0x142>(bv, bj, bp);  // row_bcast:15
  dpp_step<0x143>(bv, bj, bp);  // row_bcast:31 -> lane 63 holds result
}

// One wave per batch. JV shortest-augmenting-path, bit-faithful to reference.
// Column mapping: 0-based col n = 256*k4 + 4*lane + c  (float4 loads), slot e = 4*k4+c.
template <bool PRECOMP>
__global__ __launch_bounds__(64) void hungarian_kernel(const float* __restrict__ outputs,
                                                       const float* __restrict__ targets,
                                                       const float* __restrict__ cost,
                                                       int* __restrict__ out) {
  __shared__ int p_lds[N + 1];
  __shared__ int way_lds[N + 1];
  __shared__ int qq[T];
  __shared__ float tb[T * 4];
  __shared__ int tc[T];

  int b = blockIdx.x;
  int lane = threadIdx.x;

  for (int j = lane; j <= N; j += 64) p_lds[j] = 0;
  if (!PRECOMP) {
    const float* tr = targets + (size_t)(b * T + lane) * 5;
    tb[lane * 4 + 0] = tr[0];
    tb[lane * 4 + 1] = tr[1];
    tb[lane * 4 + 2] = tr[2];
    tb[lane * 4 + 3] = tr[3];
    tc[lane] = (int)tr[4];
  }

  float u_reg = 0.0f;  // u[lane+1] lives in lane's register
  float v[16], minv[16];
#pragma unroll
  for (int e = 0; e < 16; ++e) v[e] = 0.0f;

  const float* cost_b = PRECOMP ? (cost + (size_t)b * T * NP) : nullptr;
  const float* obase = outputs + (size_t)b * N * L;

  float4 c4[4];
  auto load_row = [&](int trow) {
    if (PRECOMP) {
      const float* crow = cost_b + (size_t)trow * NP;
#pragma unroll
      for (int k4 = 0; k4 < 4; ++k4) {
        int idx = (k4 << 8) + (lane << 2);
        idx = idx > (NP - 4) ? (NP - 4) : idx;  // clamp into padded row
        c4[k4] = *reinterpret_cast<const float4*>(crow + idx);
      }
    } else {
      float tx0 = tb[trow * 4 + 0], ty0 = tb[trow * 4 + 1];
      float tx1 = tb[trow * 4 + 2], ty1 = tb[trow * 4 + 3];
      int cls = tc[trow];
#pragma unroll
      for (int k4 = 0; k4 < 4; ++k4) {
        float tmp[4];
#pragma unroll
        for (int cc = 0; cc < 4; ++cc) {
          int n0 = (k4 << 8) + (lane << 2) + cc;
          if (n0 < N) {
            const float* orow = obase + (size_t)n0 * L;
            float4 box = *reinterpret_cast<const float4*>(orow);
            float pc = orow[5 + cls];
            tmp[cc] = cost_elem(box.x, box.y, box.z, box.w, pc, tx0, ty0, tx1, ty1);
          } else {
            tmp[cc] = 0.0f;
          }
        }
        c4[k4] = make_float4(tmp[0], tmp[1], tmp[2], tmp[3]);
      }
    }
  };

  __syncthreads();

  for (int i = 1; i <= T; ++i) {
#pragma unroll
    for (int e = 0; e < 16; ++e) minv[e] = BIGF;
    unsigned usedmask = 0;
    bool visited = false;
    int j0 = 0;
    int p0 = i;
    load_row(i - 1);  // first row's loads in flight

    for (int guard = 0; guard <= T + 2; ++guard) {
      // mark column j0 used; row p0 joins visited set (j0==0 -> row i)
      if (j0 > 0) {
        int jj = j0 - 1;
        if (lane == ((jj >> 2) & 63)) usedmask |= 1u << ((((unsigned)jj >> 8) << 2) | (jj & 3));
      }
      visited = visited || (lane == p0 - 1);
      float ui0 = __int_as_float(__builtin_amdgcn_readlane(__float_as_int(u_reg), p0 - 1));

      // candidates: reference-exact cur/minv; track improvements, defer way writes
      float bv = BIGF;
      int bj = N;  // sentinel (never wins: bv==BIGF can't beat a real min)
      unsigned impmask = 0;
#pragma unroll
      for (int k4 = 0; k4 < 4; ++k4) {
#pragma unroll
        for (int cc = 0; cc < 4; ++cc) {
          int e = (k4 << 2) | cc;
          int n0 = (k4 << 8) + (lane << 2) + cc;
          if (n0 < N && !((usedmask >> e) & 1u)) {
            float cv = (&c4[k4].x)[cc];
            float cur = (cv - ui0) - v[e];
            if (cur < minv[e]) {
              minv[e] = cur;
              impmask |= 1u << e;
            }
            if (minv[e] < bv) {  // strict <: first-index tie-break (ascending j/lane)
              bv = minv[e];
              bj = n0 + 1;
            }
          }
        }
      }

      // gather p[candidate] first (DS in-order: don't queue it behind way writes)
      int bp = p_lds[bj];
      // deferred way writes (execute in DS pipe during the DPP chain)
#pragma unroll
      for (int k4 = 0; k4 < 4; ++k4) {
#pragma unroll
        for (int cc = 0; cc < 4; ++cc) {
          int e = (k4 << 2) | cc;
          if ((impmask >> e) & 1u) way_lds[(k4 << 8) + (lane << 2) + cc + 1] = j0;
        }
      }

      wave_argmin(bv, bj, bp);
      float delta = __int_as_float(__builtin_amdgcn_readlane(__float_as_int(bv), 63));
      int j1 = __builtin_amdgcn_readlane(bj, 63);
      int p1 = __builtin_amdgcn_readlane(bp, 63);

      // issue next row's loads before the update VALU (latency hides under it)
      if (p1 != 0) load_row(p1 - 1);

      // reference-exact potential updates (registers only)
      if (visited) u_reg += delta;
#pragma unroll
      for (int e = 0; e < 16; ++e) {
        if ((usedmask >> e) & 1u) v[e] -= delta;
        else minv[e] -= delta;
      }

      j0 = j1;
      p0 = p1;
      if (p0 == 0) break;
    }

    // augment along way[] chain (uniform LDS reads; lane 0 writes)
    int jc = j0;
    for (int guard = 0; guard <= T + 2 && jc != 0; ++guard) {
      int jn = way_lds[jc];
      int pv = (jn == 0) ? i : p_lds[jn];
      if (lane == 0) p_lds[jc] = pv;
      jc = jn;
    }
  }

  __syncthreads();
  // extract q: p[j] = row assigned to column j (1-indexed)
  for (int j = 1 + lane; j <= N; j += 64) {
    int r = p_lds[j];
    if (r > 0) qq[r - 1] = j - 1;
  }
  __syncthreads();
  // sort pairs by query index: rank of q_t among all q (distinct values)
  int qt = qq[lane];
  int rank = 0;
  for (int s = 0; s < T; ++s) rank += (qq[s] < qt) ? 1 : 0;
  out[b * T + rank] = qt;            // i_idx (sorted query indices)
  out[B * T + b * T + rank] = lane;  // j_idx (target per sorted position)
}

extern "C" void kernel_launch(void* const* d_in, const int* in_sizes, int n_in,
                              void* d_out, int out_size, void* d_ws, size_t ws_size,
                              hipStream_t stream) {
  const float* outputs = (const float*)d_in[0];
  const float* targets = (const float*)d_in[1];
  int* out = (int*)d_out;

  size_t cost_bytes = (size_t)B * T * NP * sizeof(float);
  if (ws_size >= cost_bytes) {
    float* cost = (float*)d_ws;
    cost_kernel<<<dim3((N + 255) / 256, B), 256, 0, stream>>>(outputs, targets, cost);
    hungarian_kernel<true><<<B, 64, 0, stream>>>(outputs, targets, cost, out);
  } else {
    hungarian_kernel<false><<<B, 64, 0, stream>>>(outputs, targets, nullptr, out);
  }
}